// Round 11
// baseline (443.633 us; speedup 1.0000x reference)
//
#include <hip/hip_runtime.h>

#define LOG2E 1.44269504088896340736f

typedef _Float16 half2_t __attribute__((ext_vector_type(2)));

__device__ __forceinline__ float rlf(float v, int lane) {
    return __int_as_float(__builtin_amdgcn_readlane(__float_as_int(v), lane));
}
__device__ __forceinline__ unsigned rlu(unsigned v, int lane) {
    return (unsigned)__builtin_amdgcn_readlane((int)v, lane);
}
__device__ __forceinline__ unsigned pack2(float a, float b) {
    half2_t v; v.x = (_Float16)a; v.y = (_Float16)b;   // RNE (setup only)
    return __builtin_bit_cast(unsigned, v);
}
__device__ __forceinline__ half2_t ubc(unsigned u) {
    return __builtin_bit_cast(half2_t, u);
}

// Cross-half partner (lane^32) on the VALU pipe. permlane32_swap builtin
// returns both post-swap registers; r[0]^r[1]^own == partner bit-exactly
// under either operand convention (round-9 verified PASS). Keep this form.
__device__ __forceinline__ float swap_half(float v) {
#if __has_builtin(__builtin_amdgcn_permlane32_swap)
    const unsigned u = __builtin_bit_cast(unsigned, v);
    auto r = __builtin_amdgcn_permlane32_swap(u, u, false, false);
    return __builtin_bit_cast(float, (unsigned)(r[0] ^ r[1] ^ u));
#else
    return __shfl_xor(v, 32, 64);     // DS fallback (round-5 proven)
#endif
}

// Neighbor (lane^1) via DPP quad_perm [1,0,3,2] — VALU, hazard-handled.
__device__ __forceinline__ float xor1_dpp(float v) {
    return __int_as_float(__builtin_amdgcn_mov_dpp(
        __float_as_int(v), 0xB1, 0xF, 0xF, true));
}

// One wave per sequence, grid 1024 = 1 wave/SIMD chip-wide (round-4 lesson:
// occupancy axis closed; VGPR pressure is a non-constraint at 1 wave/SIMD).
// f16-packed matvec via v_dot2_f32_f16 (round-5). Step loop DS-free except
// one fire-and-forget psum write (round-3: DS pipe per-CU shared). VALU
// cross-half exchange (round-9). Round-11: 8 dot accumulators (chain depth
// 8 -> 4, path -16 cyc); raw h to psum with W_out folded into epilogue FMAs.
__global__ __launch_bounds__(64, 1) void lstm_pl_kernel(
    const float* __restrict__ x,      // [B, T]
    const float* __restrict__ W_ih,   // [128]
    const float* __restrict__ W_hh,   // [128, 32]
    const float* __restrict__ b_ih,   // [128]
    const float* __restrict__ b_hh,   // [128]
    const float* __restrict__ W_out,  // [32]
    const float* __restrict__ b_out,  // [1]
    float* __restrict__ out,          // [B, T]
    int T)
{
    __shared__ float psum[64 * 68];   // [step][lane] raw h (lanes<32 valid)

    const int b = blockIdx.x;
    const int l = threadIdx.x;        // 0..63
    const int r0 = l;                 // i (l<32) / f (l>=32): sigmoid rows
    const int r1 = l + 64;            // g (l<32) / o (l>=32)
    const bool lo = (l < 32);

    const float sc0 = -LOG2E;                           // sigmoid prescale
    const float sc1 = lo ? (-2.0f * LOG2E) : (-LOG2E);  // tanh / sigmoid

    // Pack prescaled W_hh rows into f16 pairs: 32 resident VGPRs.
    unsigned w0u[16], w1u[16];
#pragma unroll
    for (int m = 0; m < 16; ++m) {
        w0u[m] = pack2(W_hh[r0 * 32 + 2 * m] * sc0,
                       W_hh[r0 * 32 + 2 * m + 1] * sc0);
        w1u[m] = pack2(W_hh[r1 * 32 + 2 * m] * sc1,
                       W_hh[r1 * 32 + 2 * m + 1] * sc1);
    }
#pragma unroll
    for (int m = 0; m < 16; ++m)
        asm volatile("" : "+v"(w0u[m]), "+v"(w1u[m]));  // pin; no remat

    // Epilogue W_out tiles (8 float4 = 32 VGPRs; pressure is free here).
    float4 wout4[8];
#pragma unroll
    for (int m = 0; m < 8; ++m)
        wout4[m] = *(const float4*)(W_out + 4 * m);

    const float wih0  = W_ih[r0] * sc0;
    const float wih1  = W_ih[r1] * sc1;
    const float bias0 = (b_ih[r0] + b_hh[r0]) * sc0;
    const float bias1 = (b_ih[r1] + b_hh[r1]) * sc1;
    // s1s: lanes<32 -> -2log2e * tanh(g) = fma(-4log2e, rcp, 2log2e);
    //      lanes>=32 -> sigmoid(o) = rcp  (exactly what lower lanes need)
    const float A1s = lo ? (-4.0f * LOG2E) : 1.0f;
    const float B1s = lo ? ( 2.0f * LOG2E) : 0.0f;
    const float bout  = b_out[0];

    float h = 0.0f, cs = 0.0f;        // cs = -2*log2e*c  (scaled cell state)
    unsigned hpk = 0u;                // packed f16 (h[2m],h[2m+1]) in lane 2m

    const float* xp = x + (size_t)b * T;
    float*       op = out + (size_t)b * T;
    float xv = xp[l];

    for (int t0 = 0; t0 < T; t0 += 64) {
        const int tn = (t0 + 64 < T) ? (t0 + 64) : t0;
        float xv_next = xp[tn + l];   // prefetch next chunk

#pragma unroll 16
        for (int tu = 0; tu < 64; ++tu) {
            const float xt = rlf(xv, tu);

            // Batched broadcast: 16 packed h pairs from even lanes (<32).
            unsigned hp[16];
#pragma unroll
            for (int m = 0; m < 16; ++m)
                hp[m] = rlu(hpk, 2 * m);

            // Gate pre-activations: 8 accumulators (4/row), depth 4.
            float a0 = fmaf(wih0, xt, bias0);
            float a1 = fmaf(wih1, xt, bias1);
            float b0 = 0.0f, b1 = 0.0f;
            float c0 = 0.0f, c1 = 0.0f;
            float d0 = 0.0f, d1 = 0.0f;
#pragma unroll
            for (int m = 0; m < 16; m += 4) {
                a0 = __builtin_amdgcn_fdot2(ubc(w0u[m]),     ubc(hp[m]),     a0, false);
                a1 = __builtin_amdgcn_fdot2(ubc(w1u[m]),     ubc(hp[m]),     a1, false);
                b0 = __builtin_amdgcn_fdot2(ubc(w0u[m + 1]), ubc(hp[m + 1]), b0, false);
                b1 = __builtin_amdgcn_fdot2(ubc(w1u[m + 1]), ubc(hp[m + 1]), b1, false);
                c0 = __builtin_amdgcn_fdot2(ubc(w0u[m + 2]), ubc(hp[m + 2]), c0, false);
                c1 = __builtin_amdgcn_fdot2(ubc(w1u[m + 2]), ubc(hp[m + 2]), c1, false);
                d0 = __builtin_amdgcn_fdot2(ubc(w0u[m + 3]), ubc(hp[m + 3]), d0, false);
                d1 = __builtin_amdgcn_fdot2(ubc(w1u[m + 3]), ubc(hp[m + 3]), d1, false);
            }
            const float G0 = (a0 + b0) + (c0 + d0);
            const float G1 = (a1 + b1) + (c1 + d1);

            // s0 = sigmoid(i|f); s1s = -2log2e*tanh(g) (lo) | sigmoid(o) (hi)
            const float s0  = __builtin_amdgcn_rcpf(1.0f + __builtin_amdgcn_exp2f(G0));
            const float s1s = fmaf(A1s, __builtin_amdgcn_rcpf(
                                  1.0f + __builtin_amdgcn_exp2f(G1)), B1s);
            const float ig = s0 * s1s;           // i*(-2log2e*g), pre-swap

            // VALU cross-half exchange: lanes<32 get (f, sigmoid(o)).
            const float o0 = swap_half(s0);
            const float o1 = swap_half(s1s);
            const float to1 = o1 + o1;           // off critical path

            // cs = f*cs + i*(-2log2e*g); h = o1*tanh(c) = 2*o1*rcp - o1
            cs = fmaf(o0, cs, ig);
            const float rc = __builtin_amdgcn_rcpf(
                1.0f + __builtin_amdgcn_exp2f(cs));
            h = fmaf(to1, rc, -o1);

            // Repack for next step: lane 2m -> (h[2m], h[2m+1]); DPP + pkrtz.
            const float hn = xor1_dpp(h);
            hpk = __builtin_bit_cast(unsigned,
                      __builtin_amdgcn_cvt_pkrtz(h, hn));

            psum[tu * 68 + l] = h;               // raw h; W_out in epilogue
        }

        __syncthreads();  // single wave: cheap waitcnt; drain psum writes
        // Lane j: out[t0+j] = sum_{k<32} psum[j][k] * W_out[k]  (add->fma,
        // entries 32..63 skipped: woutv-fold moved here, round 11).
        const float4* row = (const float4*)(psum + l * 68);
        float4 s4;
        {
            float4 v4 = row[0];
            s4.x = v4.x * wout4[0].x; s4.y = v4.y * wout4[0].y;
            s4.z = v4.z * wout4[0].z; s4.w = v4.w * wout4[0].w;
        }
#pragma unroll
        for (int m = 1; m < 8; ++m) {
            float4 v4 = row[m];
            s4.x = fmaf(v4.x, wout4[m].x, s4.x);
            s4.y = fmaf(v4.y, wout4[m].y, s4.y);
            s4.z = fmaf(v4.z, wout4[m].z, s4.z);
            s4.w = fmaf(v4.w, wout4[m].w, s4.w);
        }
        op[t0 + l] = (s4.x + s4.y) + (s4.z + s4.w) + bout;
        __syncthreads();  // next chunk overwrites psum
        xv = xv_next;
    }
}

extern "C" void kernel_launch(void* const* d_in, const int* in_sizes, int n_in,
                              void* d_out, int out_size, void* d_ws, size_t ws_size,
                              hipStream_t stream) {
    const float* x     = (const float*)d_in[0];   // [1024, 2048, 1]
    const float* W_ih  = (const float*)d_in[1];   // [128, 1]
    const float* W_hh  = (const float*)d_in[2];   // [128, 32]
    const float* b_ih  = (const float*)d_in[3];   // [128]
    const float* b_hh  = (const float*)d_in[4];   // [128]
    const float* W_out = (const float*)d_in[5];   // [1, 32]
    const float* b_out = (const float*)d_in[6];   // [1]
    float* out = (float*)d_out;                   // [1024, 2048, 1]

    const int B = 1024;
    const int T = 2048;
    lstm_pl_kernel<<<B, 64, 0, stream>>>(x, W_ih, W_hh, b_ih, b_hh,
                                         W_out, b_out, out, T);
}

// Round 12
// 430.993 us; speedup vs baseline: 1.0293x; 1.0293x over previous
//
#include <hip/hip_runtime.h>

#define LOG2E 1.44269504088896340736f

typedef _Float16 half2_t __attribute__((ext_vector_type(2)));

__device__ __forceinline__ float rlf(float v, int lane) {
    return __int_as_float(__builtin_amdgcn_readlane(__float_as_int(v), lane));
}
__device__ __forceinline__ unsigned pack2(float a, float b) {
    half2_t v; v.x = (_Float16)a; v.y = (_Float16)b;   // RNE (setup only)
    return __builtin_bit_cast(unsigned, v);
}
__device__ __forceinline__ half2_t ubc(unsigned u) {
    return __builtin_bit_cast(half2_t, u);
}

// Cross-half partner (lane^32) on the VALU pipe. permlane32_swap builtin
// returns both post-swap registers; r[0]^r[1]^own == partner bit-exactly
// under either operand convention (round-9 verified PASS). Keep this form.
__device__ __forceinline__ float swap_half(float v) {
#if __has_builtin(__builtin_amdgcn_permlane32_swap)
    const unsigned u = __builtin_bit_cast(unsigned, v);
    auto r = __builtin_amdgcn_permlane32_swap(u, u, false, false);
    return __builtin_bit_cast(float, (unsigned)(r[0] ^ r[1] ^ u));
#else
    return __shfl_xor(v, 32, 64);     // DS fallback (round-5 proven)
#endif
}

// Neighbor (lane^1) via DPP quad_perm [1,0,3,2] — VALU, hazard-handled.
__device__ __forceinline__ float xor1_dpp(float v) {
    return __int_as_float(__builtin_amdgcn_mov_dpp(
        __float_as_int(v), 0xB1, 0xF, 0xF, true));
}

// One wave per sequence, grid 1024 = 1 wave/SIMD chip-wide (round-4 lesson).
// f16-packed matvec via v_dot2_f32_f16 (round-5). VALU cross-half exchange
// (round-9). Round-12: the 16-readlane h-broadcast (modeled ~120-135
// cyc/step of issue) is replaced by a software-pipelined LDS broadcast:
// every lane ds_writes hpk to a distinct precomputed slot (valid pairs at
// slots 0..15), then 4 uniform-address ds_read_b128 (broadcast, conflict-
// free) are issued at step END and consumed NEXT step via loop-carried
// uint4s. Same-wave LDS ops execute in order -> no barrier needed. DS load
// = 6 ops/step/wave (round-3's failure was 22). Dots now take VGPR operands
// (no SGPR-port constraint / readlane hazards).
__global__ __launch_bounds__(64, 1) void lstm_pl_kernel(
    const float* __restrict__ x,      // [B, T]
    const float* __restrict__ W_ih,   // [128]
    const float* __restrict__ W_hh,   // [128, 32]
    const float* __restrict__ b_ih,   // [128]
    const float* __restrict__ b_hh,   // [128]
    const float* __restrict__ W_out,  // [32]
    const float* __restrict__ b_out,  // [1]
    float* __restrict__ out,          // [B, T]
    int T)
{
    __shared__ float psum[64 * 68];            // [step][lane] raw h
    __shared__ __align__(16) unsigned hbc[80]; // h-pair broadcast buffer:
                                               // slots 0..15 valid, rest trash

    const int b = blockIdx.x;
    const int l = threadIdx.x;        // 0..63
    const int r0 = l;                 // i (l<32) / f (l>=32): sigmoid rows
    const int r1 = l + 64;            // g (l<32) / o (l>=32)
    const bool lo = (l < 32);

    const float sc0 = -LOG2E;                           // sigmoid prescale
    const float sc1 = lo ? (-2.0f * LOG2E) : (-LOG2E);  // tanh / sigmoid

    // Pack prescaled W_hh rows into f16 pairs: 32 resident VGPRs.
    unsigned w0u[16], w1u[16];
#pragma unroll
    for (int m = 0; m < 16; ++m) {
        w0u[m] = pack2(W_hh[r0 * 32 + 2 * m] * sc0,
                       W_hh[r0 * 32 + 2 * m + 1] * sc0);
        w1u[m] = pack2(W_hh[r1 * 32 + 2 * m] * sc1,
                       W_hh[r1 * 32 + 2 * m + 1] * sc1);
    }
#pragma unroll
    for (int m = 0; m < 16; ++m)
        asm volatile("" : "+v"(w0u[m]), "+v"(w1u[m]));  // pin; no remat

    // Epilogue W_out tiles.
    float4 wout4[8];
#pragma unroll
    for (int m = 0; m < 8; ++m)
        wout4[m] = *(const float4*)(W_out + 4 * m);

    const float wih0  = W_ih[r0] * sc0;
    const float wih1  = W_ih[r1] * sc1;
    const float bias0 = (b_ih[r0] + b_hh[r0]) * sc0;
    const float bias1 = (b_ih[r1] + b_hh[r1]) * sc1;
    // s1s: lanes<32 -> -2log2e * tanh(g) = fma(-4log2e, rcp, 2log2e);
    //      lanes>=32 -> sigmoid(o) = rcp  (exactly what lower lanes need)
    const float A1s = lo ? (-4.0f * LOG2E) : 1.0f;
    const float B1s = lo ? ( 2.0f * LOG2E) : 0.0f;
    const float bout  = b_out[0];

    // Every lane writes hpk somewhere unique; valid pairs (even lanes < 32)
    // land in slots 0..15, everyone else in 16..79 (never read).
    const int waddr = (lo && !(l & 1)) ? (l >> 1) : (16 + l);

    float h = 0.0f, cs = 0.0f;        // cs = -2*log2e*c  (scaled cell state)
    // Loop-carried broadcast h pairs (step 0: h == 0).
    uint4 hqA = {0,0,0,0}, hqB = {0,0,0,0}, hqC = {0,0,0,0}, hqD = {0,0,0,0};

    const float* xp = x + (size_t)b * T;
    float*       op = out + (size_t)b * T;
    float xv = xp[l];

    const uint4* hb4 = (const uint4*)hbc;

    for (int t0 = 0; t0 < T; t0 += 64) {
        const int tn = (t0 + 64 < T) ? (t0 + 64) : t0;
        float xv_next = xp[tn + l];   // prefetch next chunk

#pragma unroll 16
        for (int tu = 0; tu < 64; ++tu) {
            const float xt = rlf(xv, tu);

            // Gate pre-activations: hq* pre-read at end of prior step.
            float a0 = fmaf(wih0, xt, bias0);
            float a1 = fmaf(wih1, xt, bias1);
            float b0 = 0.0f, b1 = 0.0f;
            a0 = __builtin_amdgcn_fdot2(ubc(w0u[0]),  ubc(hqA.x), a0, false);
            b0 = __builtin_amdgcn_fdot2(ubc(w0u[1]),  ubc(hqA.y), b0, false);
            a1 = __builtin_amdgcn_fdot2(ubc(w1u[0]),  ubc(hqA.x), a1, false);
            b1 = __builtin_amdgcn_fdot2(ubc(w1u[1]),  ubc(hqA.y), b1, false);
            a0 = __builtin_amdgcn_fdot2(ubc(w0u[2]),  ubc(hqA.z), a0, false);
            b0 = __builtin_amdgcn_fdot2(ubc(w0u[3]),  ubc(hqA.w), b0, false);
            a1 = __builtin_amdgcn_fdot2(ubc(w1u[2]),  ubc(hqA.z), a1, false);
            b1 = __builtin_amdgcn_fdot2(ubc(w1u[3]),  ubc(hqA.w), b1, false);
            a0 = __builtin_amdgcn_fdot2(ubc(w0u[4]),  ubc(hqB.x), a0, false);
            b0 = __builtin_amdgcn_fdot2(ubc(w0u[5]),  ubc(hqB.y), b0, false);
            a1 = __builtin_amdgcn_fdot2(ubc(w1u[4]),  ubc(hqB.x), a1, false);
            b1 = __builtin_amdgcn_fdot2(ubc(w1u[5]),  ubc(hqB.y), b1, false);
            a0 = __builtin_amdgcn_fdot2(ubc(w0u[6]),  ubc(hqB.z), a0, false);
            b0 = __builtin_amdgcn_fdot2(ubc(w0u[7]),  ubc(hqB.w), b0, false);
            a1 = __builtin_amdgcn_fdot2(ubc(w1u[6]),  ubc(hqB.z), a1, false);
            b1 = __builtin_amdgcn_fdot2(ubc(w1u[7]),  ubc(hqB.w), b1, false);
            a0 = __builtin_amdgcn_fdot2(ubc(w0u[8]),  ubc(hqC.x), a0, false);
            b0 = __builtin_amdgcn_fdot2(ubc(w0u[9]),  ubc(hqC.y), b0, false);
            a1 = __builtin_amdgcn_fdot2(ubc(w1u[8]),  ubc(hqC.x), a1, false);
            b1 = __builtin_amdgcn_fdot2(ubc(w1u[9]),  ubc(hqC.y), b1, false);
            a0 = __builtin_amdgcn_fdot2(ubc(w0u[10]), ubc(hqC.z), a0, false);
            b0 = __builtin_amdgcn_fdot2(ubc(w0u[11]), ubc(hqC.w), b0, false);
            a1 = __builtin_amdgcn_fdot2(ubc(w1u[10]), ubc(hqC.z), a1, false);
            b1 = __builtin_amdgcn_fdot2(ubc(w1u[11]), ubc(hqC.w), b1, false);
            a0 = __builtin_amdgcn_fdot2(ubc(w0u[12]), ubc(hqD.x), a0, false);
            b0 = __builtin_amdgcn_fdot2(ubc(w0u[13]), ubc(hqD.y), b0, false);
            a1 = __builtin_amdgcn_fdot2(ubc(w1u[12]), ubc(hqD.x), a1, false);
            b1 = __builtin_amdgcn_fdot2(ubc(w1u[13]), ubc(hqD.y), b1, false);
            a0 = __builtin_amdgcn_fdot2(ubc(w0u[14]), ubc(hqD.z), a0, false);
            b0 = __builtin_amdgcn_fdot2(ubc(w0u[15]), ubc(hqD.w), b0, false);
            a1 = __builtin_amdgcn_fdot2(ubc(w1u[14]), ubc(hqD.z), a1, false);
            b1 = __builtin_amdgcn_fdot2(ubc(w1u[15]), ubc(hqD.w), b1, false);
            const float G0 = a0 + b0;
            const float G1 = a1 + b1;

            // s0 = sigmoid(i|f); s1s = -2log2e*tanh(g) (lo) | sigmoid(o) (hi)
            const float s0  = __builtin_amdgcn_rcpf(1.0f + __builtin_amdgcn_exp2f(G0));
            const float s1s = fmaf(A1s, __builtin_amdgcn_rcpf(
                                  1.0f + __builtin_amdgcn_exp2f(G1)), B1s);
            const float ig = s0 * s1s;           // i*(-2log2e*g), pre-swap

            // VALU cross-half exchange: lanes<32 get (f, sigmoid(o)).
            const float o0 = swap_half(s0);
            const float o1 = swap_half(s1s);
            const float to1 = o1 + o1;           // off critical path

            // cs = f*cs + i*(-2log2e*g); h = o1*tanh(c) = 2*o1*rcp - o1
            cs = fmaf(o0, cs, ig);
            const float rc = __builtin_amdgcn_rcpf(
                1.0f + __builtin_amdgcn_exp2f(cs));
            h = fmaf(to1, rc, -o1);

            // Pack pair, publish to LDS, pre-read next step's broadcast.
            // Same-wave LDS ops execute in order: reads below see this write.
            const float hn = xor1_dpp(h);
            const unsigned hpk = __builtin_bit_cast(unsigned,
                      __builtin_amdgcn_cvt_pkrtz(h, hn));
            hbc[waddr] = hpk;
            psum[tu * 68 + l] = h;               // raw h; W_out in epilogue
            hqA = hb4[0];                        // uniform addr = broadcast,
            hqB = hb4[1];                        // conflict-free; latency
            hqC = hb4[2];                        // overlaps step tail + next
            hqD = hb4[3];                        // step's head
        }

        __syncthreads();  // single wave: cheap; drains psum + pending reads
        // Lane j: out[t0+j] = sum_{k<32} psum[j][k] * W_out[k].
        const float4* row = (const float4*)(psum + l * 68);
        float4 s4;
        {
            float4 v4 = row[0];
            s4.x = v4.x * wout4[0].x; s4.y = v4.y * wout4[0].y;
            s4.z = v4.z * wout4[0].z; s4.w = v4.w * wout4[0].w;
        }
#pragma unroll
        for (int m = 1; m < 8; ++m) {
            float4 v4 = row[m];
            s4.x = fmaf(v4.x, wout4[m].x, s4.x);
            s4.y = fmaf(v4.y, wout4[m].y, s4.y);
            s4.z = fmaf(v4.z, wout4[m].z, s4.z);
            s4.w = fmaf(v4.w, wout4[m].w, s4.w);
        }
        op[t0 + l] = (s4.x + s4.y) + (s4.z + s4.w) + bout;
        __syncthreads();  // next chunk overwrites psum (hbc untouched)
        xv = xv_next;
    }
}

extern "C" void kernel_launch(void* const* d_in, const int* in_sizes, int n_in,
                              void* d_out, int out_size, void* d_ws, size_t ws_size,
                              hipStream_t stream) {
    const float* x     = (const float*)d_in[0];   // [1024, 2048, 1]
    const float* W_ih  = (const float*)d_in[1];   // [128, 1]
    const float* W_hh  = (const float*)d_in[2];   // [128, 32]
    const float* b_ih  = (const float*)d_in[3];   // [128]
    const float* b_hh  = (const float*)d_in[4];   // [128]
    const float* W_out = (const float*)d_in[5];   // [1, 32]
    const float* b_out = (const float*)d_in[6];   // [1]
    float* out = (float*)d_out;                   // [1024, 2048, 1]

    const int B = 1024;
    const int T = 2048;
    lstm_pl_kernel<<<B, 64, 0, stream>>>(x, W_ih, W_hh, b_ih, b_hh,
                                         W_out, b_out, out, T);
}

// Round 13
// 428.999 us; speedup vs baseline: 1.0341x; 1.0046x over previous
//
#include <hip/hip_runtime.h>

#define LOG2E 1.44269504088896340736f

typedef _Float16 half2_t __attribute__((ext_vector_type(2)));

__device__ __forceinline__ float rlf(float v, int lane) {
    return __int_as_float(__builtin_amdgcn_readlane(__float_as_int(v), lane));
}
__device__ __forceinline__ unsigned rlu(unsigned v, int lane) {
    return (unsigned)__builtin_amdgcn_readlane((int)v, lane);
}
__device__ __forceinline__ unsigned pack2(float a, float b) {
    half2_t v; v.x = (_Float16)a; v.y = (_Float16)b;   // RNE (setup only)
    return __builtin_bit_cast(unsigned, v);
}
__device__ __forceinline__ half2_t ubc(unsigned u) {
    return __builtin_bit_cast(half2_t, u);
}

// Cross-half partner (lane^32) on the VALU pipe. permlane32_swap builtin
// returns both post-swap registers; r[0]^r[1]^own == partner bit-exactly
// under either operand convention (round-9 verified PASS). Keep this form.
__device__ __forceinline__ float swap_half(float v) {
#if __has_builtin(__builtin_amdgcn_permlane32_swap)
    const unsigned u = __builtin_bit_cast(unsigned, v);
    auto r = __builtin_amdgcn_permlane32_swap(u, u, false, false);
    return __builtin_bit_cast(float, (unsigned)(r[0] ^ r[1] ^ u));
#else
    return __shfl_xor(v, 32, 64);     // DS fallback (round-5 proven)
#endif
}

// Neighbor (lane^1) via DPP quad_perm [1,0,3,2] — VALU, hazard-handled.
__device__ __forceinline__ float xor1_dpp(float v) {
    return __int_as_float(__builtin_amdgcn_mov_dpp(
        __float_as_int(v), 0xB1, 0xF, 0xF, true));
}

// One wave per sequence, grid 1024 = 1 wave/SIMD chip-wide (round-4 lesson).
// f16-packed matvec via v_dot2_f32_f16 (round-5). VALU cross-half exchange
// (round-9). Round-12 (LDS broadcast) cut busy 405->317 cyc/step but left
// ~90 cyc of DS round-trip latency exposed on the recurrence. Round-13:
// HYBRID broadcast, latency-matched to consumption order —
//   pairs 0..3  (consumed at chain head): 4 readlanes of loop-carried hpk
//                (register path, no memory latency; +~24 cyc issue),
//   pairs 4..15 (consumed 60-120 cyc into the dot chain): 3 loop-carried
//                uniform-address ds_read_b128 (broadcast, conflict-free;
//                latency hidden behind the readlane-fed dots).
__global__ __launch_bounds__(64, 1) void lstm_pl_kernel(
    const float* __restrict__ x,      // [B, T]
    const float* __restrict__ W_ih,   // [128]
    const float* __restrict__ W_hh,   // [128, 32]
    const float* __restrict__ b_ih,   // [128]
    const float* __restrict__ b_hh,   // [128]
    const float* __restrict__ W_out,  // [32]
    const float* __restrict__ b_out,  // [1]
    float* __restrict__ out,          // [B, T]
    int T)
{
    __shared__ float psum[64 * 68];            // [step][lane] raw h
    __shared__ __align__(16) unsigned hbc[80]; // h-pair broadcast buffer:
                                               // slots 4..15 read, rest trash

    const int b = blockIdx.x;
    const int l = threadIdx.x;        // 0..63
    const int r0 = l;                 // i (l<32) / f (l>=32): sigmoid rows
    const int r1 = l + 64;            // g (l<32) / o (l>=32)
    const bool lo = (l < 32);

    const float sc0 = -LOG2E;                           // sigmoid prescale
    const float sc1 = lo ? (-2.0f * LOG2E) : (-LOG2E);  // tanh / sigmoid

    // Pack prescaled W_hh rows into f16 pairs: 32 resident VGPRs.
    unsigned w0u[16], w1u[16];
#pragma unroll
    for (int m = 0; m < 16; ++m) {
        w0u[m] = pack2(W_hh[r0 * 32 + 2 * m] * sc0,
                       W_hh[r0 * 32 + 2 * m + 1] * sc0);
        w1u[m] = pack2(W_hh[r1 * 32 + 2 * m] * sc1,
                       W_hh[r1 * 32 + 2 * m + 1] * sc1);
    }
#pragma unroll
    for (int m = 0; m < 16; ++m)
        asm volatile("" : "+v"(w0u[m]), "+v"(w1u[m]));  // pin; no remat

    // Epilogue W_out tiles.
    float4 wout4[8];
#pragma unroll
    for (int m = 0; m < 8; ++m)
        wout4[m] = *(const float4*)(W_out + 4 * m);

    const float wih0  = W_ih[r0] * sc0;
    const float wih1  = W_ih[r1] * sc1;
    const float bias0 = (b_ih[r0] + b_hh[r0]) * sc0;
    const float bias1 = (b_ih[r1] + b_hh[r1]) * sc1;
    // s1s: lanes<32 -> -2log2e * tanh(g) = fma(-4log2e, rcp, 2log2e);
    //      lanes>=32 -> sigmoid(o) = rcp  (exactly what lower lanes need)
    const float A1s = lo ? (-4.0f * LOG2E) : 1.0f;
    const float B1s = lo ? ( 2.0f * LOG2E) : 0.0f;
    const float bout  = b_out[0];

    // Every lane writes hpk somewhere unique; pairs 4..15 (lanes 8,10,..,30)
    // land in slots 4..15; all other lanes park in 16..79 (never read).
    const bool pub = lo && !(l & 1) && (l >= 8);
    const int waddr = pub ? (l >> 1) : (16 + l);

    float h = 0.0f, cs = 0.0f;        // cs = -2*log2e*c  (scaled cell state)
    unsigned hpk = 0u;                // loop-carried packed pair (readlane src)
    // Loop-carried LDS-broadcast pairs 4..15 (step 0: h == 0).
    uint4 hqB = {0,0,0,0}, hqC = {0,0,0,0}, hqD = {0,0,0,0};

    const float* xp = x + (size_t)b * T;
    float*       op = out + (size_t)b * T;
    float xv = xp[l];

    const uint4* hb4 = (const uint4*)hbc;

    for (int t0 = 0; t0 < T; t0 += 64) {
        const int tn = (t0 + 64 < T) ? (t0 + 64) : t0;
        float xv_next = xp[tn + l];   // prefetch next chunk

#pragma unroll 16
        for (int tu = 0; tu < 64; ++tu) {
            const float xt = rlf(xv, tu);

            // Pairs 0..3 via readlane (register path; feeds first dots now).
            const unsigned hp0 = rlu(hpk, 0);
            const unsigned hp1 = rlu(hpk, 2);
            const unsigned hp2 = rlu(hpk, 4);
            const unsigned hp3 = rlu(hpk, 6);

            float a0 = fmaf(wih0, xt, bias0);
            float a1 = fmaf(wih1, xt, bias1);
            float b0 = 0.0f, b1 = 0.0f;
            // Readlane-fed dots first (cover LDS latency of hqB/C/D).
            a0 = __builtin_amdgcn_fdot2(ubc(w0u[0]),  ubc(hp0),   a0, false);
            b0 = __builtin_amdgcn_fdot2(ubc(w0u[1]),  ubc(hp1),   b0, false);
            a1 = __builtin_amdgcn_fdot2(ubc(w1u[0]),  ubc(hp0),   a1, false);
            b1 = __builtin_amdgcn_fdot2(ubc(w1u[1]),  ubc(hp1),   b1, false);
            a0 = __builtin_amdgcn_fdot2(ubc(w0u[2]),  ubc(hp2),   a0, false);
            b0 = __builtin_amdgcn_fdot2(ubc(w0u[3]),  ubc(hp3),   b0, false);
            a1 = __builtin_amdgcn_fdot2(ubc(w1u[2]),  ubc(hp2),   a1, false);
            b1 = __builtin_amdgcn_fdot2(ubc(w1u[3]),  ubc(hp3),   b1, false);
            // LDS-broadcast-fed dots.
            a0 = __builtin_amdgcn_fdot2(ubc(w0u[4]),  ubc(hqB.x), a0, false);
            b0 = __builtin_amdgcn_fdot2(ubc(w0u[5]),  ubc(hqB.y), b0, false);
            a1 = __builtin_amdgcn_fdot2(ubc(w1u[4]),  ubc(hqB.x), a1, false);
            b1 = __builtin_amdgcn_fdot2(ubc(w1u[5]),  ubc(hqB.y), b1, false);
            a0 = __builtin_amdgcn_fdot2(ubc(w0u[6]),  ubc(hqB.z), a0, false);
            b0 = __builtin_amdgcn_fdot2(ubc(w0u[7]),  ubc(hqB.w), b0, false);
            a1 = __builtin_amdgcn_fdot2(ubc(w1u[6]),  ubc(hqB.z), a1, false);
            b1 = __builtin_amdgcn_fdot2(ubc(w1u[7]),  ubc(hqB.w), b1, false);
            a0 = __builtin_amdgcn_fdot2(ubc(w0u[8]),  ubc(hqC.x), a0, false);
            b0 = __builtin_amdgcn_fdot2(ubc(w0u[9]),  ubc(hqC.y), b0, false);
            a1 = __builtin_amdgcn_fdot2(ubc(w1u[8]),  ubc(hqC.x), a1, false);
            b1 = __builtin_amdgcn_fdot2(ubc(w1u[9]),  ubc(hqC.y), b1, false);
            a0 = __builtin_amdgcn_fdot2(ubc(w0u[10]), ubc(hqC.z), a0, false);
            b0 = __builtin_amdgcn_fdot2(ubc(w0u[11]), ubc(hqC.w), b0, false);
            a1 = __builtin_amdgcn_fdot2(ubc(w1u[10]), ubc(hqC.z), a1, false);
            b1 = __builtin_amdgcn_fdot2(ubc(w1u[11]), ubc(hqC.w), b1, false);
            a0 = __builtin_amdgcn_fdot2(ubc(w0u[12]), ubc(hqD.x), a0, false);
            b0 = __builtin_amdgcn_fdot2(ubc(w0u[13]), ubc(hqD.y), b0, false);
            a1 = __builtin_amdgcn_fdot2(ubc(w1u[12]), ubc(hqD.x), a1, false);
            b1 = __builtin_amdgcn_fdot2(ubc(w1u[13]), ubc(hqD.y), b1, false);
            a0 = __builtin_amdgcn_fdot2(ubc(w0u[14]), ubc(hqD.z), a0, false);
            b0 = __builtin_amdgcn_fdot2(ubc(w0u[15]), ubc(hqD.w), b0, false);
            a1 = __builtin_amdgcn_fdot2(ubc(w1u[14]), ubc(hqD.z), a1, false);
            b1 = __builtin_amdgcn_fdot2(ubc(w1u[15]), ubc(hqD.w), b1, false);
            const float G0 = a0 + b0;
            const float G1 = a1 + b1;

            // s0 = sigmoid(i|f); s1s = -2log2e*tanh(g) (lo) | sigmoid(o) (hi)
            const float s0  = __builtin_amdgcn_rcpf(1.0f + __builtin_amdgcn_exp2f(G0));
            const float s1s = fmaf(A1s, __builtin_amdgcn_rcpf(
                                  1.0f + __builtin_amdgcn_exp2f(G1)), B1s);
            const float ig = s0 * s1s;           // i*(-2log2e*g), pre-swap

            // VALU cross-half exchange: lanes<32 get (f, sigmoid(o)).
            const float o0 = swap_half(s0);
            const float o1 = swap_half(s1s);
            const float to1 = o1 + o1;           // off critical path

            // cs = f*cs + i*(-2log2e*g); h = o1*tanh(c) = 2*o1*rcp - o1
            cs = fmaf(o0, cs, ig);
            const float rc = __builtin_amdgcn_rcpf(
                1.0f + __builtin_amdgcn_exp2f(cs));
            h = fmaf(to1, rc, -o1);

            // Pack pair; publish pairs 4..15 to LDS; pre-read next step's
            // broadcast (same-wave DS ops are in-order -> reads see write).
            const float hn = xor1_dpp(h);
            hpk = __builtin_bit_cast(unsigned,
                      __builtin_amdgcn_cvt_pkrtz(h, hn));
            hbc[waddr] = hpk;
            psum[tu * 68 + l] = h;               // raw h; W_out in epilogue
            hqB = hb4[1];                        // uniform addr = broadcast;
            hqC = hb4[2];                        // latency covered by next
            hqD = hb4[3];                        // step's readlane-fed dots
        }

        __syncthreads();  // single wave: cheap; drains psum + pending reads
        // Lane j: out[t0+j] = sum_{k<32} psum[j][k] * W_out[k].
        const float4* row = (const float4*)(psum + l * 68);
        float4 s4;
        {
            float4 v4 = row[0];
            s4.x = v4.x * wout4[0].x; s4.y = v4.y * wout4[0].y;
            s4.z = v4.z * wout4[0].z; s4.w = v4.w * wout4[0].w;
        }
#pragma unroll
        for (int m = 1; m < 8; ++m) {
            float4 v4 = row[m];
            s4.x = fmaf(v4.x, wout4[m].x, s4.x);
            s4.y = fmaf(v4.y, wout4[m].y, s4.y);
            s4.z = fmaf(v4.z, wout4[m].z, s4.z);
            s4.w = fmaf(v4.w, wout4[m].w, s4.w);
        }
        op[t0 + l] = (s4.x + s4.y) + (s4.z + s4.w) + bout;
        __syncthreads();  // next chunk overwrites psum (hbc untouched)
        xv = xv_next;
    }
}

extern "C" void kernel_launch(void* const* d_in, const int* in_sizes, int n_in,
                              void* d_out, int out_size, void* d_ws, size_t ws_size,
                              hipStream_t stream) {
    const float* x     = (const float*)d_in[0];   // [1024, 2048, 1]
    const float* W_ih  = (const float*)d_in[1];   // [128, 1]
    const float* W_hh  = (const float*)d_in[2];   // [128, 32]
    const float* b_ih  = (const float*)d_in[3];   // [128]
    const float* b_hh  = (const float*)d_in[4];   // [128]
    const float* W_out = (const float*)d_in[5];   // [1, 32]
    const float* b_out = (const float*)d_in[6];   // [1]
    float* out = (float*)d_out;                   // [1024, 2048, 1]

    const int B = 1024;
    const int T = 2048;
    lstm_pl_kernel<<<B, 64, 0, stream>>>(x, W_ih, W_hh, b_ih, b_hh,
                                         W_out, b_out, out, T);
}